// Round 3
// baseline (2204.516 us; speedup 1.0000x reference)
//
#include <hip/hip_runtime.h>

#define NU 10000
#define NREV_DST 8000

// ws layout (floats) — keep total ~51.2 MB (proven to fit):
//  [0,1024)                  Bstate
//  [1024,5632)               delta_banks[9][512]
//  [5632,10240)              W_banks[9][512]   (layout n*8+k)
//  [10240,10256)             barrier words (unsigned cnt, gen)
//  [12288, +10,240,000)      allu [NU][16][64]
//  [OFF_EMBS, +2,560,000)    embS scratch (table for the CURRENT call)
#define OFF_DELTA 1024
#define OFF_W     5632
#define OFF_BAR   10240
#define OFF_ALLU  12288
#define OFF_EMBS  (OFF_ALLU + (size_t)NU * 1024)

__device__ __forceinline__ float rlane(float v, int l) {
    return __int_as_float(__builtin_amdgcn_readlane(__float_as_int(v), l));
}

__device__ __forceinline__ void grid_barrier(unsigned* cnt, unsigned* gen, unsigned nb) {
    __syncthreads();
    if (threadIdx.x == 0) {
        __threadfence();  // release: delta atomics globally visible
        unsigned g0 = __hip_atomic_load(gen, __ATOMIC_RELAXED, __HIP_MEMORY_SCOPE_AGENT);
        unsigned a  = __hip_atomic_fetch_add(cnt, 1u, __ATOMIC_RELAXED, __HIP_MEMORY_SCOPE_AGENT);
        if (a == nb - 1u) {
            __hip_atomic_store(cnt, 0u, __ATOMIC_RELAXED, __HIP_MEMORY_SCOPE_AGENT);
            __threadfence();
            __hip_atomic_fetch_add(gen, 1u, __ATOMIC_RELAXED, __HIP_MEMORY_SCOPE_AGENT);
        } else {
            while (__hip_atomic_load(gen, __ATOMIC_RELAXED, __HIP_MEMORY_SCOPE_AGENT) == g0)
                __builtin_amdgcn_s_sleep(2);
        }
        __threadfence();  // acquire
    }
    __syncthreads();
}

// out[r][d] = sum_e E[r][e] * S[e][d]  (the reference low_new transform, verified r2)
__global__ __launch_bounds__(256) void embS_kernel(
    const float* __restrict__ E, const float* __restrict__ Sg,
    float* __restrict__ out, int nrows)
{
    const int tid = threadIdx.x, w = tid >> 6, lane = tid & 63;
    float Sc[64];
#pragma unroll
    for (int e = 0; e < 64; ++e) Sc[e] = Sg[e * 64 + lane];
    const int nw = gridDim.x * 4;
    for (int r0 = blockIdx.x * 4 + w; r0 < nrows; r0 += nw) {
        const int r = __builtin_amdgcn_readfirstlane(r0);
        const float* row = E + (size_t)r * 64;
        float acc = 0.f;
#pragma unroll
        for (int e = 0; e < 64; ++e) acc = fmaf(row[e], Sc[e], acc);
        out[(size_t)r * 64 + lane] = acc;
    }
}

__global__ __launch_bounds__(256) void init_kernel(float* __restrict__ ws,
                                                   const float* __restrict__ Bin)
{
    const int t = threadIdx.x;
    for (int i = t; i < 1024; i += 256) ws[i] = Bin[i];
    for (int i = t; i < 9 * 512; i += 256) ws[OFF_DELTA + i] = 0.f;
    if (t < 16) ((unsigned*)(ws + OFF_BAR))[t] = 0u;
}

// One fused routing call: 3 iterations with internal grid barriers.
// NB blocks x 4 waves, one user per wave per pass (users = gw + p*nwaves).
template <int N, int K, int NB, int BANK0, int LASTCALL, int WPE>
__global__ __launch_bounds__(256, WPE) void route_call(
    const float* __restrict__ embS, const int* __restrict__ idx,
    float* __restrict__ ws, int slot0)
{
    float* Bstate      = ws;
    float* delta_banks = ws + OFF_DELTA;
    float* W_banks     = ws + OFF_W;
    unsigned* bar      = (unsigned*)(ws + OFF_BAR);
    float* allu        = ws + OFF_ALLU;

    // per-wave slab [N][65]: row-major, stride 65 -> conflict-free for both
    // wave-row writes/reads (phase A) and per-lane-row walks (phase D).
    __shared__ float s_slab[4][N * 65];
    __shared__ float s_red[4][K * 64];
    __shared__ float sB[K][64];

    const int tid = threadIdx.x, w = tid >> 6, lane = tid & 63;
    const int nwaves = NB * 4;

    for (int t = tid; t < K * 64; t += 256)
        sB[t >> 6][t & 63] = Bstate[(t >> 6) * 128 + (t & 63)];
    __syncthreads();

    for (int iter = 0; iter < 3; ++iter) {
        const int bank = BANK0 + iter;
        float* Wb = W_banks + (size_t)bank * 512;
        const bool do_delta = !(LASTCALL && iter == 2);
        const bool do_high  = (iter == 2);

        // ---- W = softmax_n(B) for this iter. Every block writes identical
        // values to a FRESH bank (agent stores -> coherence point; never
        // previously cached => no stale-L2 hazard). Read back via s_load.
        for (int k = w; k < K; k += 4) {
            float v = (lane < N) ? sB[k][lane] : -3.4e38f;
            float m = v;
#pragma unroll
            for (int off = 32; off >= 1; off >>= 1) m = fmaxf(m, __shfl_xor(m, off, 64));
            const float e = (lane < N) ? expf(v - m) : 0.f;
            float s = e;
#pragma unroll
            for (int off = 32; off >= 1; off >>= 1) s += __shfl_xor(s, off, 64);
            __hip_atomic_store(&Wb[lane * 8 + k], e / s,
                               __ATOMIC_RELAXED, __HIP_MEMORY_SCOPE_AGENT);
        }
        __syncthreads();  // own-block W writes drained before any s_load of Wb

        float dreg[K];
#pragma unroll
        for (int k = 0; k < K; ++k) dreg[k] = 0.f;

        for (int u0 = blockIdx.x * 4 + w; u0 < NU; u0 += nwaves) {
            const int u = __builtin_amdgcn_readfirstlane(u0);
            const int* uidx = idx + u * N;

            // ---- phase A: raw[k][d=lane] = sum_n W[n][k] * embS[idx[n]][lane]
            // rows uniform -> coalesced 256B broadcast loads; also stage to slab.
            float raw[K];
#pragma unroll
            for (int k = 0; k < K; ++k) raw[k] = 0.f;
#pragma unroll
            for (int r0 = 0; r0 < N; r0 += 8) {
                float ev[8];
#pragma unroll
                for (int i = 0; i < 8; ++i)
                    if (r0 + i < N) {
                        const int row = uidx[r0 + i];
                        ev[i] = embS[(size_t)row * 64 + lane];
                    }
#pragma unroll
                for (int i = 0; i < 8; ++i)
                    if (r0 + i < N) {
                        s_slab[w][(r0 + i) * 65 + lane] = ev[i];
#pragma unroll
                        for (int k = 0; k < K; ++k)
                            raw[k] = fmaf(Wb[(r0 + i) * 8 + k], ev[i], raw[k]);
                    }
            }

            // ---- squash
            float sq = 0.f;
#pragma unroll
            for (int k = 0; k < K; ++k) sq = fmaf(raw[k], raw[k], sq);
            const float f = (sq / (1.0f + sq)) / sqrtf(sq + 1e-9f);
            float hi[K];
#pragma unroll
            for (int k = 0; k < K; ++k) hi[k] = f * raw[k];

            if (do_high) {
#pragma unroll
                for (int k = 0; k < K; ++k)
                    allu[(size_t)u * 1024 + (slot0 + k) * 64 + lane] = hi[k];
            }

            // ---- phase D: dreg[k][n=lane] += sum_d slab[n][d] * hi[k][d]
            if (do_delta && lane < N) {
#pragma unroll
                for (int d4 = 0; d4 < 16; ++d4) {
                    float e4[4];
#pragma unroll
                    for (int j = 0; j < 4; ++j)
                        e4[j] = s_slab[w][lane * 65 + d4 * 4 + j];
#pragma unroll
                    for (int j = 0; j < 4; ++j) {
#pragma unroll
                        for (int k = 0; k < K; ++k)
                            dreg[k] = fmaf(e4[j], rlane(hi[k], d4 * 4 + j), dreg[k]);
                    }
                }
            }
        }

        if (do_delta) {
            // block reduce -> one atomic per (k,n) per block
#pragma unroll
            for (int k = 0; k < K; ++k) s_red[w][k * 64 + lane] = dreg[k];
            __syncthreads();
            for (int t = tid; t < K * 64; t += 256) {
                const float s = s_red[0][t] + s_red[1][t] + s_red[2][t] + s_red[3][t];
                if ((t & 63) < N) atomicAdd(&delta_banks[(size_t)bank * 512 + t], s);
            }
            grid_barrier(bar, bar + 1, (unsigned)NB);
            // B update (every block, identical arithmetic)
            for (int t = tid; t < K * 64; t += 256) {
                if ((t & 63) < N) {
                    const float d = __hip_atomic_load(&delta_banks[(size_t)bank * 512 + t],
                                                      __ATOMIC_RELAXED, __HIP_MEMORY_SCOPE_AGENT);
                    sB[t >> 6][t & 63] += d;
                }
            }
            __syncthreads();
        }
    }

    // hand B to the next call (kernel-end flush makes it visible)
    if (!LASTCALL && blockIdx.x == 0) {
        for (int t = tid; t < K * 64; t += 256)
            Bstate[(t >> 6) * 128 + (t & 63)] = sB[t >> 6][t & 63];
    }
}

__global__ __launch_bounds__(256) void attn_kernel(
    const float* __restrict__ allu, const float* __restrict__ M1g,
    const float* __restrict__ M2g, float* __restrict__ out)
{
    __shared__ float sM1[64 * 65];
    __shared__ float sU[4][16 * 64];
    const int tid = threadIdx.x, w = tid >> 6, lane = tid & 63;
    for (int i = tid; i < 4096; i += 256)
        sM1[(i >> 6) * 65 + (i & 63)] = M1g[i];
    __syncthreads();
    const int u = blockIdx.x * 4 + w;
    if (u >= NU) return;
    for (int i = 0; i < 16; ++i)
        sU[w][i * 64 + lane] = allu[(size_t)u * 1024 + i * 64 + lane];
    const float m2 = M2g[lane];
    float acc[16];
#pragma unroll
    for (int i = 0; i < 16; ++i) acc[i] = 0.f;
    for (int d = 0; d < 64; ++d) {
        const float m1v = sM1[d * 65 + lane];
#pragma unroll
        for (int i = 0; i < 16; ++i) acc[i] = fmaf(sU[w][i * 64 + d], m1v, acc[i]);
    }
    float s2[16];
#pragma unroll
    for (int i = 0; i < 16; ++i) {
        float c = tanhf(acc[i]) * m2;
#pragma unroll
        for (int off = 32; off >= 1; off >>= 1) c += __shfl_xor(c, off, 64);
        s2[i] = c * c;
    }
    float mx = 0.f;  // 8 padded slots have s=0
#pragma unroll
    for (int i = 0; i < 16; ++i) mx = fmaxf(mx, s2[i]);
    float den = 8.f * expf(-mx);
    float att[16];
#pragma unroll
    for (int i = 0; i < 16; ++i) { att[i] = expf(s2[i] - mx); den += att[i]; }
    const float inv = 1.0f / den;
    float o = 0.f;
#pragma unroll
    for (int i = 0; i < 16; ++i) o = fmaf(att[i] * inv, sU[w][i * 64 + lane], o);
    out[(size_t)u * 64 + lane] = o;
}

__global__ __launch_bounds__(256) void review_kernel(
    const float* __restrict__ tag, const int* __restrict__ idx, float* __restrict__ out)
{
    const int tid = threadIdx.x, w = tid >> 6, lane = tid & 63;
    const int r = blockIdx.x * 4 + w;
    if (r >= NREV_DST) return;
    float acc = 0.f;
    for (int j = 0; j < 20; ++j) {
        const int t = idx[r * 20 + j];
        acc += tag[(size_t)t * 64 + lane];
    }
    out[(size_t)r * 64 + lane] = acc / 20.0f;
}

extern "C" void kernel_launch(void* const* d_in, const int* in_sizes, int n_in,
                              void* d_out, int out_size, void* d_ws, size_t ws_size,
                              hipStream_t stream)
{
    const float* review_embed = (const float*)d_in[0];
    const float* tag_embed    = (const float*)d_in[1];
    const int*   idx_urt      = (const int*)d_in[2];
    const int*   idx_uqt      = (const int*)d_in[3];
    const int*   idx_uprt     = (const int*)d_in[4];
    const int*   idx_rht      = (const int*)d_in[5];
    const float* B_in         = (const float*)d_in[6];
    const float* S_g          = (const float*)d_in[7];
    const float* M1           = (const float*)d_in[8];
    const float* M2           = (const float*)d_in[9];

    float* ws   = (float*)d_ws;
    float* embS = ws + OFF_EMBS;
    float* out  = (float*)d_out;

    const dim3 mb(256), one(1), pg(512);

    // Co-residency math (grid <= capacity, verified by LDS accounting):
    // call1: LDS/block = 4*64*65*4 + 4*6*64*4 + 6*64*4 = 74,240 B -> 2 blocks/CU -> cap 512; use 500 (2000 waves * 5 users = 10000 exact)
    // call2: LDS/block = 4*32*65*4 + 4*5*64*4 + 5*64*4 = 39,680 B -> 3 blocks/CU -> cap 768; use 625 (2500 waves * 4 users = 10000 exact)
    // call3: LDS/block = 4*50*65*4 + 4*5*64*4 + 5*64*4 = 58,400 B -> 2 blocks/CU -> cap 512; use 500

    hipLaunchKernelGGL(embS_kernel, pg, mb, 0, stream, review_embed, S_g, embS, 30000);
    hipLaunchKernelGGL(init_kernel, one, mb, 0, stream, ws, B_in);

    hipLaunchKernelGGL((route_call<64, 6, 500, 0, 0, 2>), dim3(500), mb, 0, stream,
                       embS, idx_urt, ws, 0);

    hipLaunchKernelGGL(embS_kernel, pg, mb, 0, stream, tag_embed, S_g, embS, 40000);
    hipLaunchKernelGGL((route_call<32, 5, 625, 3, 0, 3>), dim3(625), mb, 0, stream,
                       embS, idx_uqt, ws, 6);

    hipLaunchKernelGGL(embS_kernel, pg, mb, 0, stream, review_embed, S_g, embS, 30000);
    hipLaunchKernelGGL((route_call<50, 5, 500, 6, 1, 2>), dim3(500), mb, 0, stream,
                       embS, idx_uprt, ws, 11);

    hipLaunchKernelGGL(attn_kernel, dim3((NU + 3) / 4), mb, 0, stream,
                       ws + OFF_ALLU, M1, M2, out);
    hipLaunchKernelGGL(review_kernel, dim3((NREV_DST + 3) / 4), mb, 0, stream,
                       tag_embed, idx_rht, out + (size_t)NU * 64);
}

// Round 4
// 1172.711 us; speedup vs baseline: 1.8798x; 1.8798x over previous
//
#include <hip/hip_runtime.h>

#define NU 10000
#define NREV_DST 8000
#define MAIN_BLOCKS 2500   // 2500 blocks x 4 waves = 10000 users, one user per wave

// ws float layout (round-1 proven):
//   [0)      Bstate[8*128]   = 1024
//   [1024)   delta_acc[512]
//   [1536)   Wbuf[64*8]      = 512   (TRANSPOSED: W[n][k] at n*8+k)
//   [2048)   allu[NU*16*64]  = 10,240,000

template <int N, int K>
__global__ __launch_bounds__(256, 4) void main_iter(
    const float* __restrict__ emb, const int* __restrict__ idx,
    const float* __restrict__ Sg, const float* __restrict__ Wg,
    float* __restrict__ delta_acc, float* __restrict__ allu,
    int slot0, int write_high, int write_delta)
{
    // S XOR-swizzled: element (r,c) at r*64 + (c ^ ((r&15)<<2))  [bits2-5 XOR]
    // -> conflict-free for B's column b32 reads AND C's row b128 reads.
    __shared__ float s_S[64 * 64];
    __shared__ float s_slab[4][64 * 10];  // D: 8-wide e-chunks, stride 10
    __shared__ float s_g[4][K * 64];      // g, then hs (wave-private, sequential reuse)
    __shared__ float s_h[4][K * 64];      // hi

    const int tid  = threadIdx.x;
    const int w    = tid >> 6;
    const int lane = tid & 63;

    for (int i = tid; i < 64 * 64; i += 256) {
        const int r = i >> 6, c = i & 63;
        s_S[r * 64 + (c ^ ((r & 15) << 2))] = Sg[i];
    }
    __syncthreads();

    const int u = __builtin_amdgcn_readfirstlane((int)blockIdx.x * 4 + w);
    const int* uidx = idx + u * N;

    // ---- phase A: g[k][e=lane] = sum_n W[n][k] * emb[idx[n]][lane]
    // rows wave-uniform -> coalesced 256B broadcast loads; W via s_load (const).
    float g[K];
#pragma unroll
    for (int k = 0; k < K; ++k) g[k] = 0.f;
#pragma unroll
    for (int r0 = 0; r0 < N; r0 += 16) {
        float ev[16];
#pragma unroll
        for (int i = 0; i < 16; ++i)
            if (r0 + i < N) {
                const int row = uidx[r0 + i];          // s_load (uniform)
                ev[i] = emb[(size_t)row * 64 + lane];  // coalesced row
            }
#pragma unroll
        for (int i = 0; i < 16; ++i)
            if (r0 + i < N) {
#pragma unroll
                for (int k = 0; k < K; ++k)
                    g[k] = fmaf(Wg[(r0 + i) * 8 + k], ev[i], g[k]);
            }
    }

    // ---- phase B: raw[k][d=lane] = sum_e g[k][e] * S[e][d]
    // g broadcast via same-address ds_read_b128; S columns via swizzled b32.
#pragma unroll
    for (int k = 0; k < K; ++k) s_g[w][k * 64 + lane] = g[k];
    float raw[K];
#pragma unroll
    for (int k = 0; k < K; ++k) raw[k] = 0.f;
#pragma unroll
    for (int e0 = 0; e0 < 64; e0 += 4) {
        float sv[4];
#pragma unroll
        for (int j = 0; j < 4; ++j) {
            const int e = e0 + j;
            sv[j] = s_S[e * 64 + (lane ^ ((e & 15) << 2))];
        }
#pragma unroll
        for (int k = 0; k < K; ++k) {
            const float4 g4 = *(const float4*)&s_g[w][k * 64 + e0];
            raw[k] = fmaf(g4.x, sv[0], raw[k]);
            raw[k] = fmaf(g4.y, sv[1], raw[k]);
            raw[k] = fmaf(g4.z, sv[2], raw[k]);
            raw[k] = fmaf(g4.w, sv[3], raw[k]);
        }
    }

    // ---- squash
    float sq = 0.f;
#pragma unroll
    for (int k = 0; k < K; ++k) sq = fmaf(raw[k], raw[k], sq);
    const float f = (sq / (1.0f + sq)) / sqrtf(sq + 1e-9f);
    float hi[K];
#pragma unroll
    for (int k = 0; k < K; ++k) hi[k] = f * raw[k];

    if (write_high) {
#pragma unroll
        for (int k = 0; k < K; ++k)
            allu[(size_t)u * 1024 + (slot0 + k) * 64 + lane] = hi[k];
    }

    if (write_delta) {
        // ---- phase C: hs[k][e=lane] = sum_d hi[k][d] * S[lane][d]
        // own-row b128 swizzled S reads + hi broadcast via ds_read_b128.
#pragma unroll
        for (int k = 0; k < K; ++k) s_h[w][k * 64 + lane] = hi[k];
        float hs[K];
#pragma unroll
        for (int k = 0; k < K; ++k) hs[k] = 0.f;
#pragma unroll
        for (int c4 = 0; c4 < 16; ++c4) {
            const float4 sv = *(const float4*)&s_S[lane * 64 + ((c4 ^ (lane & 15)) << 2)];
#pragma unroll
            for (int k = 0; k < K; ++k) {
                const float4 h4 = *(const float4*)&s_h[w][k * 64 + c4 * 4];
                hs[k] = fmaf(h4.x, sv.x, hs[k]);
                hs[k] = fmaf(h4.y, sv.y, hs[k]);
                hs[k] = fmaf(h4.z, sv.z, hs[k]);
                hs[k] = fmaf(h4.w, sv.w, hs[k]);
            }
        }
#pragma unroll
        for (int k = 0; k < K; ++k) s_g[w][k * 64 + lane] = hs[k];  // reuse as hS buf

        // ---- phase D: delta[k][n=lane] += sum_e emb[idx[n]][e] * hs[k][e]
        // 8-wide e-chunks staged to stride-10 slab; hs broadcast via b128.
        float dreg[K];
#pragma unroll
        for (int k = 0; k < K; ++k) dreg[k] = 0.f;

        constexpr int RP = (N + 15) / 16;
        const int rr = lane >> 2, jj = lane & 3;
        int rows[RP];
#pragma unroll
        for (int p = 0; p < RP; ++p) {
            const int r = p * 16 + rr;
            rows[p] = (N % 16 == 0 || r < N) ? uidx[r] : 0;
        }

        for (int ec = 0; ec < 8; ++ec) {
            const int e0 = ec * 8;
#pragma unroll
            for (int p = 0; p < RP; ++p) {
                const int r = p * 16 + rr;
                if (N % 16 == 0 || r < N) {
                    const float2 v =
                        *(const float2*)(emb + (size_t)rows[p] * 64 + e0 + jj * 2);
                    *(float2*)&s_slab[w][r * 10 + jj * 2] = v;
                }
            }
            const float2 v0 = *(const float2*)&s_slab[w][lane * 10 + 0];
            const float2 v1 = *(const float2*)&s_slab[w][lane * 10 + 2];
            const float2 v2 = *(const float2*)&s_slab[w][lane * 10 + 4];
            const float2 v3 = *(const float2*)&s_slab[w][lane * 10 + 6];
#pragma unroll
            for (int k = 0; k < K; ++k) {
                const float4 hA = *(const float4*)&s_g[w][k * 64 + e0];
                const float4 hB = *(const float4*)&s_g[w][k * 64 + e0 + 4];
                dreg[k] = fmaf(v0.x, hA.x, dreg[k]);
                dreg[k] = fmaf(v0.y, hA.y, dreg[k]);
                dreg[k] = fmaf(v1.x, hA.z, dreg[k]);
                dreg[k] = fmaf(v1.y, hA.w, dreg[k]);
                dreg[k] = fmaf(v2.x, hB.x, dreg[k]);
                dreg[k] = fmaf(v2.y, hB.y, dreg[k]);
                dreg[k] = fmaf(v3.x, hB.z, dreg[k]);
                dreg[k] = fmaf(v3.y, hB.w, dreg[k]);
            }
        }

        // cross-wave reduce (reuse slabs), one atomic per (k,n) per block
        __syncthreads();  // all waves done (uniform trip counts)
#pragma unroll
        for (int k = 0; k < K; ++k) s_slab[w][k * 64 + lane] = dreg[k];
        __syncthreads();
        for (int t = tid; t < K * 64; t += 256) {
            const float s = s_slab[0][t] + s_slab[1][t] + s_slab[2][t] + s_slab[3][t];
            if ((t & 63) < N) atomicAdd(&delta_acc[t], s);  // lanes>=N garbage -> masked
        }
    }
}

// Apply delta -> B, zero delta, compute next softmax W (transposed layout n*8+k).
__global__ __launch_bounds__(1024) void update_kernel(
    float* __restrict__ Bstate, float* __restrict__ delta_acc,
    const float* __restrict__ Bin, float* __restrict__ Wout,
    int init, int Kc, int nc, int Kn, int nn)
{
    __shared__ float sB[1024];
    const int t = threadIdx.x;
    float b = init ? Bin[t] : Bstate[t];
    const int k = t >> 7, n = t & 127;
    float d = 0.f;
    if (!init && k < Kc && n < nc) d = delta_acc[k * 64 + n];
    __syncthreads();
    if (t < 512) delta_acc[t] = 0.f;  // fresh accumulator for next main launch
    b += d;
    Bstate[t] = b;
    sB[t] = b;
    __syncthreads();
    const int wv = t >> 6, lane = t & 63;
    if (wv < Kn) {
        float v = (lane < nn) ? sB[wv * 128 + lane] : -3.4e38f;
        float m = v;
#pragma unroll
        for (int off = 32; off >= 1; off >>= 1) m = fmaxf(m, __shfl_xor(m, off, 64));
        const float e = (lane < nn) ? expf(v - m) : 0.f;
        float s = e;
#pragma unroll
        for (int off = 32; off >= 1; off >>= 1) s += __shfl_xor(s, off, 64);
        Wout[lane * 8 + wv] = e / s;  // transposed: W[n][k]
    }
}

// block 0: init Bstate/delta + W0 softmax (K=6, n=64). blocks 1..: review_out rows.
__global__ __launch_bounds__(256) void init_review_kernel(
    float* __restrict__ ws, const float* __restrict__ Bin,
    const float* __restrict__ tag, const int* __restrict__ idx,
    float* __restrict__ rout)
{
    const int t = threadIdx.x, w = t >> 6, lane = t & 63;
    if (blockIdx.x == 0) {
        __shared__ float sB[1024];
        for (int i = t; i < 1024; i += 256) { const float b = Bin[i]; ws[i] = b; sB[i] = b; }
        for (int i = t; i < 512; i += 256) ws[1024 + i] = 0.f;
        __syncthreads();
#pragma unroll
        for (int wv = w; wv < 6; wv += 4) {
            float v = sB[wv * 128 + lane];  // n=64: all lanes valid
            float m = v;
#pragma unroll
            for (int off = 32; off >= 1; off >>= 1) m = fmaxf(m, __shfl_xor(m, off, 64));
            const float e = expf(v - m);
            float s = e;
#pragma unroll
            for (int off = 32; off >= 1; off >>= 1) s += __shfl_xor(s, off, 64);
            ws[1536 + lane * 8 + wv] = e / s;  // transposed W[n][k]
        }
        return;
    }
    const int r = (blockIdx.x - 1) * 4 + w;
    if (r >= NREV_DST) return;
    float acc = 0.f;
    for (int j = 0; j < 20; ++j) {
        const int tg = idx[r * 20 + j];
        acc += tag[(size_t)tg * 64 + lane];
    }
    rout[(size_t)r * 64 + lane] = acc / 20.0f;
}

__global__ __launch_bounds__(256) void attn_kernel(
    const float* __restrict__ allu, const float* __restrict__ M1g,
    const float* __restrict__ M2g, float* __restrict__ out)
{
    __shared__ float sM1[64 * 65];
    __shared__ float sU[4][16 * 64];
    const int tid = threadIdx.x, w = tid >> 6, lane = tid & 63;
    for (int i = tid; i < 4096; i += 256)
        sM1[(i >> 6) * 65 + (i & 63)] = M1g[i];
    __syncthreads();
    const int u = blockIdx.x * 4 + w;
    if (u >= NU) return;
    for (int i = 0; i < 16; ++i)
        sU[w][i * 64 + lane] = allu[(size_t)u * 1024 + i * 64 + lane];
    const float m2 = M2g[lane];
    float acc[16];
#pragma unroll
    for (int i = 0; i < 16; ++i) acc[i] = 0.f;
    for (int d = 0; d < 64; ++d) {
        const float m1v = sM1[d * 65 + lane];
#pragma unroll
        for (int i = 0; i < 16; ++i) acc[i] = fmaf(sU[w][i * 64 + d], m1v, acc[i]);
    }
    float s2[16];
#pragma unroll
    for (int i = 0; i < 16; ++i) {
        float c = tanhf(acc[i]) * m2;
#pragma unroll
        for (int off = 32; off >= 1; off >>= 1) c += __shfl_xor(c, off, 64);
        s2[i] = c * c;
    }
    float mx = 0.f;  // 8 padded slots have s=0
#pragma unroll
    for (int i = 0; i < 16; ++i) mx = fmaxf(mx, s2[i]);
    float den = 8.f * expf(-mx);
    float att[16];
#pragma unroll
    for (int i = 0; i < 16; ++i) { att[i] = expf(s2[i] - mx); den += att[i]; }
    const float inv = 1.0f / den;
    float o = 0.f;
#pragma unroll
    for (int i = 0; i < 16; ++i) o = fmaf(att[i] * inv, sU[w][i * 64 + lane], o);
    out[(size_t)u * 64 + lane] = o;
}

extern "C" void kernel_launch(void* const* d_in, const int* in_sizes, int n_in,
                              void* d_out, int out_size, void* d_ws, size_t ws_size,
                              hipStream_t stream)
{
    const float* review_embed = (const float*)d_in[0];
    const float* tag_embed    = (const float*)d_in[1];
    const int*   idx_urt      = (const int*)d_in[2];
    const int*   idx_uqt      = (const int*)d_in[3];
    const int*   idx_uprt     = (const int*)d_in[4];
    const int*   idx_rht      = (const int*)d_in[5];
    const float* B_in         = (const float*)d_in[6];
    const float* S_g          = (const float*)d_in[7];
    const float* M1           = (const float*)d_in[8];
    const float* M2           = (const float*)d_in[9];

    float* ws     = (float*)d_ws;
    float* Bstate = ws;
    float* delta  = ws + 1024;
    float* Wbuf   = ws + 1536;
    float* allu   = ws + 2048;
    float* out    = (float*)d_out;

    const dim3 mg(MAIN_BLOCKS), mb(256);
    const dim3 one(1), ub(1024);

    // init B/delta/W0 + review output (independent work) in one launch
    hipLaunchKernelGGL(init_review_kernel, dim3(1 + (NREV_DST + 3) / 4), mb, 0, stream,
                       ws, B_in, tag_embed, idx_rht, out + (size_t)NU * 64);

    // call 1: review_embed[idx_urt], n=64, K=6, slots 0..5
    for (int itr = 0; itr < 3; ++itr) {
        hipLaunchKernelGGL((main_iter<64, 6>), mg, mb, 0, stream,
                           review_embed, idx_urt, S_g, Wbuf, delta, allu,
                           0, (itr == 2) ? 1 : 0, 1);
        const int Kn = (itr == 2) ? 5 : 6;
        const int nn = (itr == 2) ? 32 : 64;
        hipLaunchKernelGGL(update_kernel, one, ub, 0, stream,
                           Bstate, delta, B_in, Wbuf, 0, 6, 64, Kn, nn);
    }
    // call 2: tag_embed[idx_uqt], n=32, K=5, slots 6..10
    for (int itr = 0; itr < 3; ++itr) {
        hipLaunchKernelGGL((main_iter<32, 5>), mg, mb, 0, stream,
                           tag_embed, idx_uqt, S_g, Wbuf, delta, allu,
                           6, (itr == 2) ? 1 : 0, 1);
        const int nn = (itr == 2) ? 50 : 32;
        hipLaunchKernelGGL(update_kernel, one, ub, 0, stream,
                           Bstate, delta, B_in, Wbuf, 0, 5, 32, 5, nn);
    }
    // call 3: review_embed[idx_uprt], n=50, K=5, slots 11..15
    for (int itr = 0; itr < 3; ++itr) {
        const int last = (itr == 2);
        hipLaunchKernelGGL((main_iter<50, 5>), mg, mb, 0, stream,
                           review_embed, idx_uprt, S_g, Wbuf, delta, allu,
                           11, last, last ? 0 : 1);
        if (!last)
            hipLaunchKernelGGL(update_kernel, one, ub, 0, stream,
                               Bstate, delta, B_in, Wbuf, 0, 5, 50, 5, 50);
    }

    hipLaunchKernelGGL(attn_kernel, dim3((NU + 3) / 4), mb, 0, stream, allu, M1, M2, out);
}

// Round 7
// 711.410 us; speedup vs baseline: 3.0988x; 1.6484x over previous
//
#include <hip/hip_runtime.h>

#define NU 10000
#define NREV_DST 8000
#define MAIN_BLOCKS 512
#define TW (MAIN_BLOCKS * 4)
#define UPW ((NU + TW - 1) / TW)

// ws float layout (R0-proven):
//   [0)      Bstate[8*128]   = 1024
//   [1024)   delta_acc[512]
//   [1536)   Wbuf[8*64]      = 512
//   [2048)   allu[NU*16*64]  = 10,240,000   (slots: call1->0..5, call2->6..10, call3->11..15)

template <int N, int K>
__global__ __launch_bounds__(256) void main_iter(
    const float* __restrict__ emb, const int* __restrict__ idx,
    const float* __restrict__ Sg, const float* __restrict__ Wg,
    float* __restrict__ delta_acc, float* __restrict__ allu,
    int slot0, int write_high, int write_delta)
{
    constexpr int NC = (N + 31) / 32;
    constexpr int P  = NC * 32;

    // S XOR-swizzled (R4-proven): element (r,c) at r*64 + (c ^ ((r&15)<<2)).
    // Conflict-free column b32 reads (phase B) AND row b128 reads (phase C).
    __shared__ float s_S[64 * 64];
    __shared__ float s_emb[4][32 * 65];
    __shared__ float s_g[4][K * 64];
    __shared__ float s_h[4][K * 64];

    const int tid  = threadIdx.x;
    const int w    = tid >> 6;
    const int lane = tid & 63;
    const int gw   = blockIdx.x * 4 + w;

    // stage S swizzled
    for (int i = tid; i < 64 * 64; i += 256) {
        const int r = i >> 6, c = i & 63;
        s_S[r * 64 + (c ^ ((r & 15) << 2))] = Sg[i];
    }
    __syncthreads();

    float dreg[NC][K];
#pragma unroll
    for (int c = 0; c < NC; ++c)
#pragma unroll
        for (int k = 0; k < K; ++k) dreg[c][k] = 0.f;

    auto stage = [&](int u, int c, int m) {
        const int npass = (m + 3) >> 2;
        for (int p = 0; p < npass; ++p) {
            const int r = p * 4 + (lane >> 4);
            if (r < m) {
                const int row = idx[u * N + c * 32 + r];
                const float4 v =
                    *reinterpret_cast<const float4*>(emb + (size_t)row * 64 + (lane & 15) * 4);
                float* dst = &s_emb[w][r * 65 + (lane & 15) * 4];
                dst[0] = v.x; dst[1] = v.y; dst[2] = v.z; dst[3] = v.w;
            }
        }
    };

    for (int it = 0; it < UPW; ++it) {
        const int u = gw + it * TW;
        if (u < NU) {
            // ---- phase A: g[k][e=lane] = sum_n W[k][n] * emb[n][e]   (R0 verbatim)
            float g[K];
#pragma unroll
            for (int k = 0; k < K; ++k) g[k] = 0.f;
#pragma unroll
            for (int c = 0; c < NC; ++c) {
                const int m = (N - c * 32 < 32) ? (N - c * 32) : 32;
                stage(u, c, m);
                for (int r = 0; r < m; ++r) {
                    const float ev = s_emb[w][r * 65 + lane];
#pragma unroll
                    for (int k = 0; k < K; ++k)
                        g[k] = fmaf(Wg[k * 64 + c * 32 + r], ev, g[k]);  // uniform -> s_load
                }
            }
            // ---- phase B: raw[k][d=lane] = sum_e g[k][e] * S[e][d]
            // (R4-proven: swizzled col reads + float4 g broadcasts; e ascending = R0 order)
#pragma unroll
            for (int k = 0; k < K; ++k) s_g[w][k * 64 + lane] = g[k];
            float raw[K];
#pragma unroll
            for (int k = 0; k < K; ++k) raw[k] = 0.f;
#pragma unroll 4
            for (int e0 = 0; e0 < 64; e0 += 4) {
                float sv[4];
#pragma unroll
                for (int j = 0; j < 4; ++j) {
                    const int e = e0 + j;
                    sv[j] = s_S[e * 64 + (lane ^ ((e & 15) << 2))];
                }
#pragma unroll
                for (int k = 0; k < K; ++k) {
                    const float4 g4 = *(const float4*)&s_g[w][k * 64 + e0];
                    raw[k] = fmaf(g4.x, sv[0], raw[k]);
                    raw[k] = fmaf(g4.y, sv[1], raw[k]);
                    raw[k] = fmaf(g4.z, sv[2], raw[k]);
                    raw[k] = fmaf(g4.w, sv[3], raw[k]);
                }
            }
            // ---- squash (R0 verbatim)
            float sq = 0.f;
#pragma unroll
            for (int k = 0; k < K; ++k) sq = fmaf(raw[k], raw[k], sq);
            const float f = (sq / (1.0f + sq)) / sqrtf(sq + 1e-9f);
            float hi[K];
#pragma unroll
            for (int k = 0; k < K; ++k) hi[k] = f * raw[k];
            if (write_high) {
#pragma unroll
                for (int k = 0; k < K; ++k)
                    allu[(size_t)u * 1024 + (slot0 + k) * 64 + lane] = hi[k];
            }
            if (write_delta) {
                // ---- phase C: hS[k][e=lane] = sum_d hi[k][d] * S[e][d]
                // (R4-proven: swizzled row b128 + float4 hi broadcasts; d ascending = R0 order)
#pragma unroll
                for (int k = 0; k < K; ++k) s_h[w][k * 64 + lane] = hi[k];
                float hs[K];
#pragma unroll
                for (int k = 0; k < K; ++k) hs[k] = 0.f;
#pragma unroll 4
                for (int c4 = 0; c4 < 16; ++c4) {
                    const float4 sv = *(const float4*)&s_S[lane * 64 + ((c4 ^ (lane & 15)) << 2)];
#pragma unroll
                    for (int k = 0; k < K; ++k) {
                        const float4 h4 = *(const float4*)&s_h[w][k * 64 + c4 * 4];
                        hs[k] = fmaf(h4.x, sv.x, hs[k]);
                        hs[k] = fmaf(h4.y, sv.y, hs[k]);
                        hs[k] = fmaf(h4.z, sv.z, hs[k]);
                        hs[k] = fmaf(h4.w, sv.w, hs[k]);
                    }
                }
#pragma unroll
                for (int k = 0; k < K; ++k) s_g[w][k * 64 + lane] = hs[k];  // reuse as hS buf
                // ---- phase D: delta[k][n] += sum_e emb[n][e] * hS[k][e]
                // (R0 skeleton: lane=(row, e-half), chunk-resident trick; float4 hS reads)
                const int nl = lane & 31, h = lane >> 5;
#pragma unroll
                for (int cc = NC - 1; cc >= 0; --cc) {
                    const int m = (N - cc * 32 < 32) ? (N - cc * 32) : 32;
                    if (cc != NC - 1) stage(u, cc, m);  // last chunk still resident
                    if (nl < m) {
#pragma unroll
                        for (int eq = 0; eq < 8; ++eq) {
                            const int e = h * 32 + eq * 4;
                            const float e0v = s_emb[w][nl * 65 + e + 0];
                            const float e1v = s_emb[w][nl * 65 + e + 1];
                            const float e2v = s_emb[w][nl * 65 + e + 2];
                            const float e3v = s_emb[w][nl * 65 + e + 3];
#pragma unroll
                            for (int k = 0; k < K; ++k) {
                                const float4 h4 = *(const float4*)&s_g[w][k * 64 + e];
                                dreg[cc][k] = fmaf(e0v, h4.x, dreg[cc][k]);
                                dreg[cc][k] = fmaf(e1v, h4.y, dreg[cc][k]);
                                dreg[cc][k] = fmaf(e2v, h4.z, dreg[cc][k]);
                                dreg[cc][k] = fmaf(e3v, h4.w, dreg[cc][k]);
                            }
                        }
                    }
                }
            }
        }
    }

    if (write_delta) {
        __syncthreads();  // all waves done with s_emb (uniform trip counts)
        float* red = &s_emb[w][0];
        const int nl = lane & 31;
#pragma unroll
        for (int cc = 0; cc < NC; ++cc) {
#pragma unroll
            for (int k = 0; k < K; ++k) {
                const float v = dreg[cc][k] + __shfl_xor(dreg[cc][k], 32, 64);
                if (lane < 32) red[k * P + cc * 32 + nl] = v;
            }
        }
        __syncthreads();
        for (int t = tid; t < K * P; t += 256) {
            const float s = s_emb[0][t] + s_emb[1][t] + s_emb[2][t] + s_emb[3][t];
            const int k = t / P, n = t % P;
            atomicAdd(&delta_acc[k * 64 + n], s);
        }
    }
}

// Apply delta -> B, zero delta, compute next softmax W.  (R0 verbatim)
__global__ __launch_bounds__(1024) void update_kernel(
    float* __restrict__ Bstate, float* __restrict__ delta_acc,
    const float* __restrict__ Bin, float* __restrict__ Wout,
    int init, int Kc, int nc, int Kn, int nn)
{
    __shared__ float sB[1024];
    const int t = threadIdx.x;
    float b = init ? Bin[t] : Bstate[t];
    const int k = t >> 7, n = t & 127;
    float d = 0.f;
    if (!init && k < Kc && n < nc) d = delta_acc[k * 64 + n];
    __syncthreads();
    if (t < 512) delta_acc[t] = 0.f;  // fresh accumulator for next main launch
    b += d;
    Bstate[t] = b;
    sB[t] = b;
    __syncthreads();
    const int wv = t >> 6, lane = t & 63;
    if (wv < Kn) {
        float v = (lane < nn) ? sB[wv * 128 + lane] : -3.4e38f;
        float m = v;
#pragma unroll
        for (int off = 32; off >= 1; off >>= 1) m = fmaxf(m, __shfl_xor(m, off, 64));
        const float e = (lane < nn) ? expf(v - m) : 0.f;
        float s = e;
#pragma unroll
        for (int off = 32; off >= 1; off >>= 1) s += __shfl_xor(s, off, 64);
        Wout[wv * 64 + lane] = e / s;
    }
}

__global__ __launch_bounds__(256) void attn_kernel(
    const float* __restrict__ allu, const float* __restrict__ M1g,
    const float* __restrict__ M2g, float* __restrict__ out)
{
    __shared__ float sM1[64 * 65];
    __shared__ float sU[4][16 * 64];
    const int tid = threadIdx.x, w = tid >> 6, lane = tid & 63;
    for (int i = tid; i < 4096; i += 256)
        sM1[(i >> 6) * 65 + (i & 63)] = M1g[i];
    __syncthreads();
    const int u = blockIdx.x * 4 + w;
    if (u >= NU) return;
    for (int i = 0; i < 16; ++i)
        sU[w][i * 64 + lane] = allu[(size_t)u * 1024 + i * 64 + lane];
    const float m2 = M2g[lane];
    float acc[16];
#pragma unroll
    for (int i = 0; i < 16; ++i) acc[i] = 0.f;
    for (int d = 0; d < 64; ++d) {
        const float m1v = sM1[d * 65 + lane];
#pragma unroll
        for (int i = 0; i < 16; ++i) acc[i] = fmaf(sU[w][i * 64 + d], m1v, acc[i]);
    }
    float s2[16];
#pragma unroll
    for (int i = 0; i < 16; ++i) {
        float c = tanhf(acc[i]) * m2;
#pragma unroll
        for (int off = 32; off >= 1; off >>= 1) c += __shfl_xor(c, off, 64);
        s2[i] = c * c;
    }
    float mx = 0.f;  // 8 padded slots have s=0
#pragma unroll
    for (int i = 0; i < 16; ++i) mx = fmaxf(mx, s2[i]);
    float den = 8.f * expf(-mx);
    float att[16];
#pragma unroll
    for (int i = 0; i < 16; ++i) { att[i] = expf(s2[i] - mx); den += att[i]; }
    const float inv = 1.0f / den;
    float o = 0.f;
#pragma unroll
    for (int i = 0; i < 16; ++i) o = fmaf(att[i] * inv, sU[w][i * 64 + lane], o);
    out[(size_t)u * 64 + lane] = o;
}

__global__ __launch_bounds__(256) void review_kernel(
    const float* __restrict__ tag, const int* __restrict__ idx, float* __restrict__ out)
{
    const int tid = threadIdx.x, w = tid >> 6, lane = tid & 63;
    const int r = blockIdx.x * 4 + w;
    if (r >= NREV_DST) return;
    float acc = 0.f;
    for (int j = 0; j < 20; ++j) {
        const int t = idx[r * 20 + j];
        acc += tag[(size_t)t * 64 + lane];
    }
    out[(size_t)r * 64 + lane] = acc / 20.0f;
}

extern "C" void kernel_launch(void* const* d_in, const int* in_sizes, int n_in,
                              void* d_out, int out_size, void* d_ws, size_t ws_size,
                              hipStream_t stream)
{
    const float* review_embed = (const float*)d_in[0];
    const float* tag_embed    = (const float*)d_in[1];
    const int*   idx_urt      = (const int*)d_in[2];
    const int*   idx_uqt      = (const int*)d_in[3];
    const int*   idx_uprt     = (const int*)d_in[4];
    const int*   idx_rht      = (const int*)d_in[5];
    const float* B_in         = (const float*)d_in[6];
    const float* S_g          = (const float*)d_in[7];
    const float* M1           = (const float*)d_in[8];
    const float* M2           = (const float*)d_in[9];

    float* ws     = (float*)d_ws;
    float* Bstate = ws;
    float* delta  = ws + 1024;
    float* Wbuf   = ws + 1536;
    float* allu   = ws + 2048;
    float* out    = (float*)d_out;

    const dim3 mg(MAIN_BLOCKS), mb(256);
    const dim3 one(1), ub(1024);

    // init: copy B, zero delta, W for call1 (K=6, n=64)
    hipLaunchKernelGGL(update_kernel, one, ub, 0, stream,
                       Bstate, delta, B_in, Wbuf, 1, 0, 0, 6, 64);

    // call 1: review_embed[idx_urt], n=64, K=6, slots 0..5
    for (int itr = 0; itr < 3; ++itr) {
        hipLaunchKernelGGL((main_iter<64, 6>), mg, mb, 0, stream,
                           review_embed, idx_urt, S_g, Wbuf, delta, allu,
                           0, (itr == 2) ? 1 : 0, 1);
        const int Kn = (itr == 2) ? 5 : 6;
        const int nn = (itr == 2) ? 32 : 64;
        hipLaunchKernelGGL(update_kernel, one, ub, 0, stream,
                           Bstate, delta, B_in, Wbuf, 0, 6, 64, Kn, nn);
    }
    // call 2: tag_embed[idx_uqt], n=32, K=5, slots 6..10
    for (int itr = 0; itr < 3; ++itr) {
        hipLaunchKernelGGL((main_iter<32, 5>), mg, mb, 0, stream,
                           tag_embed, idx_uqt, S_g, Wbuf, delta, allu,
                           6, (itr == 2) ? 1 : 0, 1);
        const int nn = (itr == 2) ? 50 : 32;
        hipLaunchKernelGGL(update_kernel, one, ub, 0, stream,
                           Bstate, delta, B_in, Wbuf, 0, 5, 32, 5, nn);
    }
    // call 3: review_embed[idx_uprt], n=50, K=5, slots 11..15
    for (int itr = 0; itr < 3; ++itr) {
        const int last = (itr == 2);
        hipLaunchKernelGGL((main_iter<50, 5>), mg, mb, 0, stream,
                           review_embed, idx_uprt, S_g, Wbuf, delta, allu,
                           11, last, last ? 0 : 1);
        if (!last)
            hipLaunchKernelGGL(update_kernel, one, ub, 0, stream,
                               Bstate, delta, B_in, Wbuf, 0, 5, 50, 5, 50);
    }

    hipLaunchKernelGGL(attn_kernel, dim3((NU + 3) / 4), mb, 0, stream, allu, M1, M2, out);
    hipLaunchKernelGGL(review_kernel, dim3((NREV_DST + 3) / 4), mb, 0, stream,
                       tag_embed, idx_rht, out + (size_t)NU * 64);
}

// Round 8
// 710.349 us; speedup vs baseline: 3.1034x; 1.0015x over previous
//
#include <hip/hip_runtime.h>

#define NU 10000
#define NREV_DST 8000
#define MAIN_BLOCKS 512
#define TW (MAIN_BLOCKS * 4)
#define UPW ((NU + TW - 1) / TW)

// ws float layout (R0-proven):
//   [0)      Bstate[8*128]   = 1024
//   [1024)   delta_acc[512]
//   [1536)   Wbuf[8*64]      = 512
//   [2048)   allu[NU*16*64]  = 10,240,000   (slots: call1->0..5, call2->6..10, call3->11..15)

template <int N, int K>
__global__ __launch_bounds__(256, 4) void main_iter(   // min 4 waves/EU -> VGPR cap 128 (occupancy cliff, m69)
    const float* __restrict__ emb, const int* __restrict__ idx,
    const float* __restrict__ Sg, const float* __restrict__ Wg,
    float* __restrict__ delta_acc, float* __restrict__ allu,
    int slot0, int write_high, int write_delta)
{
    constexpr int NC = (N + 31) / 32;
    constexpr int P  = NC * 32;

    // S XOR-swizzled (R4-proven): element (r,c) at r*64 + (c ^ ((r&15)<<2)).
    // Conflict-free column b32 reads (phase B) AND row b128 reads (phase C).
    __shared__ float s_S[64 * 64];
    __shared__ float s_emb[4][32 * 65];
    __shared__ float s_g[4][K * 64];
    __shared__ float s_h[4][K * 64];

    const int tid  = threadIdx.x;
    const int w    = tid >> 6;
    const int lane = tid & 63;
    const int gw   = blockIdx.x * 4 + w;

    // stage S swizzled
    for (int i = tid; i < 64 * 64; i += 256) {
        const int r = i >> 6, c = i & 63;
        s_S[r * 64 + (c ^ ((r & 15) << 2))] = Sg[i];
    }
    __syncthreads();

    float dreg[NC][K];
#pragma unroll
    for (int c = 0; c < NC; ++c)
#pragma unroll
        for (int k = 0; k < K; ++k) dreg[c][k] = 0.f;

    auto stage = [&](int u, int c, int m) {
        const int npass = (m + 3) >> 2;
        for (int p = 0; p < npass; ++p) {
            const int r = p * 4 + (lane >> 4);
            if (r < m) {
                const int row = idx[u * N + c * 32 + r];
                const float4 v =
                    *reinterpret_cast<const float4*>(emb + (size_t)row * 64 + (lane & 15) * 4);
                float* dst = &s_emb[w][r * 65 + (lane & 15) * 4];
                dst[0] = v.x; dst[1] = v.y; dst[2] = v.z; dst[3] = v.w;
            }
        }
    };

    for (int it = 0; it < UPW; ++it) {
        const int u = gw + it * TW;
        if (u < NU) {
            // ---- phase A: g[k][e=lane] = sum_n W[k][n] * emb[n][e]   (R0 verbatim)
            float g[K];
#pragma unroll
            for (int k = 0; k < K; ++k) g[k] = 0.f;
#pragma unroll
            for (int c = 0; c < NC; ++c) {
                const int m = (N - c * 32 < 32) ? (N - c * 32) : 32;
                stage(u, c, m);
                for (int r = 0; r < m; ++r) {
                    const float ev = s_emb[w][r * 65 + lane];
#pragma unroll
                    for (int k = 0; k < K; ++k)
                        g[k] = fmaf(Wg[k * 64 + c * 32 + r], ev, g[k]);  // uniform -> s_load
                }
            }
            // ---- phase B: raw[k][d=lane] = sum_e g[k][e] * S[e][d]
            // (R7-proven: swizzled col reads + float4 g broadcasts; e ascending order)
#pragma unroll
            for (int k = 0; k < K; ++k) s_g[w][k * 64 + lane] = g[k];
            float raw[K];
#pragma unroll
            for (int k = 0; k < K; ++k) raw[k] = 0.f;
#pragma unroll 4
            for (int e0 = 0; e0 < 64; e0 += 4) {
                float sv[4];
#pragma unroll
                for (int j = 0; j < 4; ++j) {
                    const int e = e0 + j;
                    sv[j] = s_S[e * 64 + (lane ^ ((e & 15) << 2))];
                }
#pragma unroll
                for (int k = 0; k < K; ++k) {
                    const float4 g4 = *(const float4*)&s_g[w][k * 64 + e0];
                    raw[k] = fmaf(g4.x, sv[0], raw[k]);
                    raw[k] = fmaf(g4.y, sv[1], raw[k]);
                    raw[k] = fmaf(g4.z, sv[2], raw[k]);
                    raw[k] = fmaf(g4.w, sv[3], raw[k]);
                }
            }
            // ---- squash (R0 verbatim)
            float sq = 0.f;
#pragma unroll
            for (int k = 0; k < K; ++k) sq = fmaf(raw[k], raw[k], sq);
            const float f = (sq / (1.0f + sq)) / sqrtf(sq + 1e-9f);
            float hi[K];
#pragma unroll
            for (int k = 0; k < K; ++k) hi[k] = f * raw[k];
            if (write_high) {
#pragma unroll
                for (int k = 0; k < K; ++k)
                    allu[(size_t)u * 1024 + (slot0 + k) * 64 + lane] = hi[k];
            }
            if (write_delta) {
                // ---- phase C: hS[k][e=lane] = sum_d hi[k][d] * S[e][d]
                // (R7-proven: swizzled row b128 + float4 hi broadcasts; d ascending order)
#pragma unroll
                for (int k = 0; k < K; ++k) s_h[w][k * 64 + lane] = hi[k];
                float hs[K];
#pragma unroll
                for (int k = 0; k < K; ++k) hs[k] = 0.f;
#pragma unroll 4
                for (int c4 = 0; c4 < 16; ++c4) {
                    const float4 sv = *(const float4*)&s_S[lane * 64 + ((c4 ^ (lane & 15)) << 2)];
#pragma unroll
                    for (int k = 0; k < K; ++k) {
                        const float4 h4 = *(const float4*)&s_h[w][k * 64 + c4 * 4];
                        hs[k] = fmaf(h4.x, sv.x, hs[k]);
                        hs[k] = fmaf(h4.y, sv.y, hs[k]);
                        hs[k] = fmaf(h4.z, sv.z, hs[k]);
                        hs[k] = fmaf(h4.w, sv.w, hs[k]);
                    }
                }
#pragma unroll
                for (int k = 0; k < K; ++k) s_g[w][k * 64 + lane] = hs[k];  // reuse as hS buf
                // ---- phase D: delta[k][n] += sum_e emb[n][e] * hS[k][e]
                // (R0 skeleton: lane=(row, e-half), chunk-resident trick; float4 hS reads)
                const int nl = lane & 31, h = lane >> 5;
#pragma unroll
                for (int cc = NC - 1; cc >= 0; --cc) {
                    const int m = (N - cc * 32 < 32) ? (N - cc * 32) : 32;
                    if (cc != NC - 1) stage(u, cc, m);  // last chunk still resident
                    if (nl < m) {
#pragma unroll
                        for (int eq = 0; eq < 8; ++eq) {
                            const int e = h * 32 + eq * 4;
                            const float e0v = s_emb[w][nl * 65 + e + 0];
                            const float e1v = s_emb[w][nl * 65 + e + 1];
                            const float e2v = s_emb[w][nl * 65 + e + 2];
                            const float e3v = s_emb[w][nl * 65 + e + 3];
#pragma unroll
                            for (int k = 0; k < K; ++k) {
                                const float4 h4 = *(const float4*)&s_g[w][k * 64 + e];
                                dreg[cc][k] = fmaf(e0v, h4.x, dreg[cc][k]);
                                dreg[cc][k] = fmaf(e1v, h4.y, dreg[cc][k]);
                                dreg[cc][k] = fmaf(e2v, h4.z, dreg[cc][k]);
                                dreg[cc][k] = fmaf(e3v, h4.w, dreg[cc][k]);
                            }
                        }
                    }
                }
            }
        }
    }

    if (write_delta) {
        __syncthreads();  // all waves done with s_emb (uniform trip counts)
        float* red = &s_emb[w][0];
        const int nl = lane & 31;
#pragma unroll
        for (int cc = 0; cc < NC; ++cc) {
#pragma unroll
            for (int k = 0; k < K; ++k) {
                const float v = dreg[cc][k] + __shfl_xor(dreg[cc][k], 32, 64);
                if (lane < 32) red[k * P + cc * 32 + nl] = v;
            }
        }
        __syncthreads();
        for (int t = tid; t < K * P; t += 256) {
            const float s = s_emb[0][t] + s_emb[1][t] + s_emb[2][t] + s_emb[3][t];
            const int k = t / P, n = t % P;
            atomicAdd(&delta_acc[k * 64 + n], s);
        }
    }
}

// Apply delta -> B, zero delta, compute next softmax W.  (R0 verbatim)
__global__ __launch_bounds__(1024) void update_kernel(
    float* __restrict__ Bstate, float* __restrict__ delta_acc,
    const float* __restrict__ Bin, float* __restrict__ Wout,
    int init, int Kc, int nc, int Kn, int nn)
{
    __shared__ float sB[1024];
    const int t = threadIdx.x;
    float b = init ? Bin[t] : Bstate[t];
    const int k = t >> 7, n = t & 127;
    float d = 0.f;
    if (!init && k < Kc && n < nc) d = delta_acc[k * 64 + n];
    __syncthreads();
    if (t < 512) delta_acc[t] = 0.f;  // fresh accumulator for next main launch
    b += d;
    Bstate[t] = b;
    sB[t] = b;
    __syncthreads();
    const int wv = t >> 6, lane = t & 63;
    if (wv < Kn) {
        float v = (lane < nn) ? sB[wv * 128 + lane] : -3.4e38f;
        float m = v;
#pragma unroll
        for (int off = 32; off >= 1; off >>= 1) m = fmaxf(m, __shfl_xor(m, off, 64));
        const float e = (lane < nn) ? expf(v - m) : 0.f;
        float s = e;
#pragma unroll
        for (int off = 32; off >= 1; off >>= 1) s += __shfl_xor(s, off, 64);
        Wout[wv * 64 + lane] = e / s;
    }
}

__global__ __launch_bounds__(256) void attn_kernel(
    const float* __restrict__ allu, const float* __restrict__ M1g,
    const float* __restrict__ M2g, float* __restrict__ out)
{
    __shared__ float sM1[64 * 65];
    __shared__ float sU[4][16 * 64];
    const int tid = threadIdx.x, w = tid >> 6, lane = tid & 63;
    for (int i = tid; i < 4096; i += 256)
        sM1[(i >> 6) * 65 + (i & 63)] = M1g[i];
    __syncthreads();
    const int u = blockIdx.x * 4 + w;
    if (u >= NU) return;
    for (int i = 0; i < 16; ++i)
        sU[w][i * 64 + lane] = allu[(size_t)u * 1024 + i * 64 + lane];
    const float m2 = M2g[lane];
    float acc[16];
#pragma unroll
    for (int i = 0; i < 16; ++i) acc[i] = 0.f;
    for (int d = 0; d < 64; ++d) {
        const float m1v = sM1[d * 65 + lane];
#pragma unroll
        for (int i = 0; i < 16; ++i) acc[i] = fmaf(sU[w][i * 64 + d], m1v, acc[i]);
    }
    float s2[16];
#pragma unroll
    for (int i = 0; i < 16; ++i) {
        float c = tanhf(acc[i]) * m2;
#pragma unroll
        for (int off = 32; off >= 1; off >>= 1) c += __shfl_xor(c, off, 64);
        s2[i] = c * c;
    }
    float mx = 0.f;  // 8 padded slots have s=0
#pragma unroll
    for (int i = 0; i < 16; ++i) mx = fmaxf(mx, s2[i]);
    float den = 8.f * expf(-mx);
    float att[16];
#pragma unroll
    for (int i = 0; i < 16; ++i) { att[i] = expf(s2[i] - mx); den += att[i]; }
    const float inv = 1.0f / den;
    float o = 0.f;
#pragma unroll
    for (int i = 0; i < 16; ++i) o = fmaf(att[i] * inv, sU[w][i * 64 + lane], o);
    out[(size_t)u * 64 + lane] = o;
}

__global__ __launch_bounds__(256) void review_kernel(
    const float* __restrict__ tag, const int* __restrict__ idx, float* __restrict__ out)
{
    const int tid = threadIdx.x, w = tid >> 6, lane = tid & 63;
    const int r = blockIdx.x * 4 + w;
    if (r >= NREV_DST) return;
    float acc = 0.f;
    for (int j = 0; j < 20; ++j) {
        const int t = idx[r * 20 + j];
        acc += tag[(size_t)t * 64 + lane];
    }
    out[(size_t)r * 64 + lane] = acc / 20.0f;
}

extern "C" void kernel_launch(void* const* d_in, const int* in_sizes, int n_in,
                              void* d_out, int out_size, void* d_ws, size_t ws_size,
                              hipStream_t stream)
{
    const float* review_embed = (const float*)d_in[0];
    const float* tag_embed    = (const float*)d_in[1];
    const int*   idx_urt      = (const int*)d_in[2];
    const int*   idx_uqt      = (const int*)d_in[3];
    const int*   idx_uprt     = (const int*)d_in[4];
    const int*   idx_rht      = (const int*)d_in[5];
    const float* B_in         = (const float*)d_in[6];
    const float* S_g          = (const float*)d_in[7];
    const float* M1           = (const float*)d_in[8];
    const float* M2           = (const float*)d_in[9];

    float* ws     = (float*)d_ws;
    float* Bstate = ws;
    float* delta  = ws + 1024;
    float* Wbuf   = ws + 1536;
    float* allu   = ws + 2048;
    float* out    = (float*)d_out;

    const dim3 mg(MAIN_BLOCKS), mb(256);
    const dim3 one(1), ub(1024);

    // init: copy B, zero delta, W for call1 (K=6, n=64)
    hipLaunchKernelGGL(update_kernel, one, ub, 0, stream,
                       Bstate, delta, B_in, Wbuf, 1, 0, 0, 6, 64);

    // call 1: review_embed[idx_urt], n=64, K=6, slots 0..5
    for (int itr = 0; itr < 3; ++itr) {
        hipLaunchKernelGGL((main_iter<64, 6>), mg, mb, 0, stream,
                           review_embed, idx_urt, S_g, Wbuf, delta, allu,
                           0, (itr == 2) ? 1 : 0, 1);
        const int Kn = (itr == 2) ? 5 : 6;
        const int nn = (itr == 2) ? 32 : 64;
        hipLaunchKernelGGL(update_kernel, one, ub, 0, stream,
                           Bstate, delta, B_in, Wbuf, 0, 6, 64, Kn, nn);
    }
    // call 2: tag_embed[idx_uqt], n=32, K=5, slots 6..10
    for (int itr = 0; itr < 3; ++itr) {
        hipLaunchKernelGGL((main_iter<32, 5>), mg, mb, 0, stream,
                           tag_embed, idx_uqt, S_g, Wbuf, delta, allu,
                           6, (itr == 2) ? 1 : 0, 1);
        const int nn = (itr == 2) ? 50 : 32;
        hipLaunchKernelGGL(update_kernel, one, ub, 0, stream,
                           Bstate, delta, B_in, Wbuf, 0, 5, 32, 5, nn);
    }
    // call 3: review_embed[idx_uprt], n=50, K=5, slots 11..15
    for (int itr = 0; itr < 3; ++itr) {
        const int last = (itr == 2);
        hipLaunchKernelGGL((main_iter<50, 5>), mg, mb, 0, stream,
                           review_embed, idx_uprt, S_g, Wbuf, delta, allu,
                           11, last, last ? 0 : 1);
        if (!last)
            hipLaunchKernelGGL(update_kernel, one, ub, 0, stream,
                               Bstate, delta, B_in, Wbuf, 0, 5, 50, 5, 50);
    }

    hipLaunchKernelGGL(attn_kernel, dim3((NU + 3) / 4), mb, 0, stream, allu, M1, M2, out);
    hipLaunchKernelGGL(review_kernel, dim3((NREV_DST + 3) / 4), mb, 0, stream,
                       tag_embed, idx_rht, out + (size_t)NU * 64);
}